// Round 1
// baseline (1532.485 us; speedup 1.0000x reference)
//
#include <hip/hip_runtime.h>

#define NROWS 8192      // BS*HEADS
#define NKEYS 512
#define KNN   32

// ---------------------------------------------------------------------------
// GEMM (NT, fp32): C[M,N] = A[M,K] * B[N,K]^T (+bias[n])
// BM=128, BN=64, BK=16, 256 threads, 8x4 outputs/thread.
// ---------------------------------------------------------------------------
__global__ __launch_bounds__(256)
void gemm_nt_f32(const float* __restrict__ A, int lda,
                 const float* __restrict__ B, int ldb,
                 float* __restrict__ C, int ldc,
                 const float* __restrict__ bias, int K) {
  __shared__ float As[16][132];   // [k][m], row padded to 132 (16B-aligned rows, spread banks)
  __shared__ float Bs[16][68];    // [k][n]
  const int tid = threadIdx.x;
  const int tx = tid & 15;        // -> n
  const int ty = tid >> 4;        // -> m
  const int m0 = blockIdx.y * 128;
  const int n0 = blockIdx.x * 64;
  const int am = tid >> 1;        // 0..127
  const int ak = (tid & 1) * 8;   // 0 or 8
  const int bn = tid >> 2;        // 0..63
  const int bk = (tid & 3) * 4;   // 0,4,8,12

  float acc[8][4];
  #pragma unroll
  for (int i = 0; i < 8; i++)
    #pragma unroll
    for (int j = 0; j < 4; j++) acc[i][j] = 0.f;

  const float* Arow = A + (size_t)(m0 + am) * lda + ak;
  const float* Brow = B + (size_t)(n0 + bn) * ldb + bk;

  for (int kt = 0; kt < K; kt += 16) {
    float4 a0 = *(const float4*)(Arow + kt);
    float4 a1 = *(const float4*)(Arow + kt + 4);
    float4 b0 = *(const float4*)(Brow + kt);
    As[ak+0][am] = a0.x; As[ak+1][am] = a0.y; As[ak+2][am] = a0.z; As[ak+3][am] = a0.w;
    As[ak+4][am] = a1.x; As[ak+5][am] = a1.y; As[ak+6][am] = a1.z; As[ak+7][am] = a1.w;
    Bs[bk+0][bn] = b0.x; Bs[bk+1][bn] = b0.y; Bs[bk+2][bn] = b0.z; Bs[bk+3][bn] = b0.w;
    __syncthreads();
    #pragma unroll
    for (int k = 0; k < 16; k++) {
      float a[8], b[4];
      *(float4*)&a[0] = *(const float4*)&As[k][ty*8];
      *(float4*)&a[4] = *(const float4*)&As[k][ty*8+4];
      *(float4*)&b[0] = *(const float4*)&Bs[k][tx*4];
      #pragma unroll
      for (int i = 0; i < 8; i++)
        #pragma unroll
        for (int j = 0; j < 4; j++)
          acc[i][j] = fmaf(a[i], b[j], acc[i][j]);
    }
    __syncthreads();
  }

  float bv[4] = {0.f, 0.f, 0.f, 0.f};
  if (bias) {
    #pragma unroll
    for (int j = 0; j < 4; j++) bv[j] = bias[n0 + tx*4 + j];
  }
  #pragma unroll
  for (int i = 0; i < 8; i++) {
    float4 o;
    o.x = acc[i][0] + bv[0];
    o.y = acc[i][1] + bv[1];
    o.z = acc[i][2] + bv[2];
    o.w = acc[i][3] + bv[3];
    *(float4*)&C[(size_t)(m0 + ty*8 + i) * ldc + n0 + tx*4] = o;
  }
}

// ---------------------------------------------------------------------------
// Top-32 of 512 per row, one wave per row. 16384 rows (8192 for s1, 8192 s2).
// Output sorted DESCENDING (matches lax.top_k order; sortedness needed for
// the (i+1)(j+1)<=32 pruning in combine).
// ---------------------------------------------------------------------------
__global__ __launch_bounds__(256)
void topk512(const float* __restrict__ s1, const float* __restrict__ s2,
             float* __restrict__ v1, int* __restrict__ i1,
             float* __restrict__ v2, int* __restrict__ i2) {
  const int wid  = (int)((blockIdx.x * blockDim.x + threadIdx.x) >> 6);
  const int lane = threadIdx.x & 63;
  const float* src; float* dv; int* di;
  if (wid < NROWS) {
    src = s1 + (size_t)wid * NKEYS; dv = v1 + (size_t)wid * KNN; di = i1 + (size_t)wid * KNN;
  } else {
    int r = wid - NROWS;
    src = s2 + (size_t)r * NKEYS;  dv = v2 + (size_t)r * KNN;  di = i2 + (size_t)r * KNN;
  }
  float v[8];
  #pragma unroll
  for (int s = 0; s < 8; s++) v[s] = src[s*64 + lane];

  float outv = 0.f; int outi = 0;
  for (int round = 0; round < KNN; round++) {
    // lane-local argmax over 8 (register-resident, unrolled)
    float m = v[0]; int ms = 0;
    #pragma unroll
    for (int s = 1; s < 8; s++) { if (v[s] > m) { m = v[s]; ms = s; } }
    int gi = ms*64 + lane;
    // wave butterfly all-reduce argmax; tie -> lower index (total order, so
    // every lane converges to the SAME winner -> invalidation is consistent)
    #pragma unroll
    for (int off = 32; off >= 1; off >>= 1) {
      float om = __shfl_xor(m, off, 64);
      int  ogi = __shfl_xor(gi, off, 64);
      if (om > m || (om == m && ogi < gi)) { m = om; gi = ogi; }
    }
    if (lane == round) { outv = m; outi = gi; }
    if ((gi & 63) == lane) {
      int s = gi >> 6;
      #pragma unroll
      for (int ss = 0; ss < 8; ss++) if (ss == s) v[ss] = -INFINITY;
    }
  }
  if (lane < KNN) { dv[lane] = outv; di[lane] = outi; }
}

// ---------------------------------------------------------------------------
// Combine: per q-row, top-32 of {a_i + b_j}. Since a,b sorted descending, a
// pair can only be top-32 if (i+1)*(j+1) <= 32 -> 119 candidates. One wave
// per row: 2 candidates/lane, bitonic sort of 128 (val,pairIdx) descending
// via shfl, take first 32, softmax, write weights + flat value indices.
// ---------------------------------------------------------------------------
__global__ __launch_bounds__(256)
void combine_topk(const float* __restrict__ v1, const int* __restrict__ i1,
                  const float* __restrict__ v2, const int* __restrict__ i2,
                  float* __restrict__ wout, int* __restrict__ idxout) {
  const int wid  = (int)((blockIdx.x * blockDim.x + threadIdx.x) >> 6);
  const int lane = threadIdx.x & 63;

  const float* a  = v1 + (size_t)wid * KNN;
  const int*   ai = i1 + (size_t)wid * KNN;
  const float* b  = v2 + (size_t)wid * KNN;
  const int*   bi = i2 + (size_t)wid * KNN;

  float cv[2]; int cidx[2];
  #pragma unroll
  for (int h = 0; h < 2; h++) {
    int t = lane + h*64;
    int i = 0, rem = t;
    while (i < 32 && rem >= 32/(i+1)) { rem -= 32/(i+1); i++; }
    if (i < 32) {               // valid candidate (t < 119)
      float av = a[i], bvv = b[rem];
      cv[h]   = av + bvv;
      cidx[h] = ai[i] * NKEYS + bi[rem];
    } else {
      cv[h] = -INFINITY; cidx[h] = 0;
    }
  }

  // bitonic sort of 128 elements (element e = 2*lane + h), descending
  #pragma unroll
  for (int k = 2; k <= 128; k <<= 1) {
    #pragma unroll
    for (int j = 64; j >= 1; j >>= 1) {
      if (j > (k >> 1)) continue;
      if (j >= 2) {
        int mdist = j >> 1;
        #pragma unroll
        for (int h = 0; h < 2; h++) {
          float ov = __shfl_xor(cv[h],   mdist, 64);
          int   oi = __shfl_xor(cidx[h], mdist, 64);
          int e = 2*lane + h;
          bool lower   = (lane & mdist) == 0;
          bool desc    = (e & k) == 0;
          bool keepmax = (lower == desc);
          bool take    = keepmax ? (ov > cv[h]) : (ov < cv[h]);
          if (take) { cv[h] = ov; cidx[h] = oi; }
        }
      } else {
        int e = 2*lane;
        bool desc = (e & k) == 0;
        bool sw = desc ? (cv[0] < cv[1]) : (cv[0] > cv[1]);
        if (sw) {
          float tv = cv[0]; cv[0] = cv[1]; cv[1] = tv;
          int  ti = cidx[0]; cidx[0] = cidx[1]; cidx[1] = ti;
        }
      }
    }
  }

  // elements 0..31 live in lanes 0..15 (both slots); element 0 is the max
  float mx = __shfl(cv[0], 0, 64);
  float e0 = (lane < 16) ? __expf(cv[0] - mx) : 0.f;
  float e1 = (lane < 16) ? __expf(cv[1] - mx) : 0.f;
  float ssum = e0 + e1;
  #pragma unroll
  for (int off = 32; off >= 1; off >>= 1) ssum += __shfl_xor(ssum, off, 64);

  if (lane < 16) {
    size_t base = (size_t)wid * KNN + 2*lane;
    wout[base]     = e0 / ssum;
    wout[base + 1] = e1 / ssum;
    idxout[base]     = cidx[0];
    idxout[base + 1] = cidx[1];
  }
}

// ---------------------------------------------------------------------------
// Gather: out[b,:] = sum_k w[b,k] * values[idx[b,k], :].  One block per b,
// 256 threads x float4 = 1024 cols. 1 GB of coalesced 4KB-row reads -> the
// HBM roofline of this problem.
// ---------------------------------------------------------------------------
__global__ __launch_bounds__(256)
void gather_wsum(const float* __restrict__ w, const int* __restrict__ idx,
                 const float* __restrict__ values, float* __restrict__ out) {
  const int b = blockIdx.x;
  const int t = threadIdx.x;
  __shared__ float sw[128];
  __shared__ int   si[128];
  if (t < 128) {
    sw[t] = w[(size_t)b*128 + t];
    si[t] = idx[(size_t)b*128 + t];
  }
  __syncthreads();
  const float4* V = (const float4*)values;   // row stride 256 float4
  float4 acc = make_float4(0.f, 0.f, 0.f, 0.f);
  #pragma unroll 8
  for (int k = 0; k < 128; k++) {
    float wk = sw[k];
    float4 v = V[(size_t)si[k] * 256 + t];
    acc.x = fmaf(wk, v.x, acc.x);
    acc.y = fmaf(wk, v.y, acc.y);
    acc.z = fmaf(wk, v.z, acc.z);
    acc.w = fmaf(wk, v.w, acc.w);
  }
  ((float4*)out)[(size_t)b*256 + t] = acc;
}

// ---------------------------------------------------------------------------
extern "C" void kernel_launch(void* const* d_in, const int* in_sizes, int n_in,
                              void* d_out, int out_size, void* d_ws, size_t ws_size,
                              hipStream_t stream) {
  const float* x      = (const float*)d_in[0];   // 2048 x 1024
  const float* Wq     = (const float*)d_in[1];   // 1024 x 1024
  const float* bq     = (const float*)d_in[2];   // 1024
  const float* keys   = (const float*)d_in[3];   // 512 x 128
  const float* values = (const float*)d_in[4];   // 262144 x 1024
  float* out = (float*)d_out;

  char* ws = (char*)d_ws;
  float* q   = (float*)(ws);                     // 8 MB   (8192 x 256)
  float* s1  = (float*)(ws + (8u  << 20));       // 16 MB  (8192 x 512)
  float* s2  = (float*)(ws + (24u << 20));       // 16 MB
  float* v1  = (float*)(ws + (40u << 20));       // 1 MB   (8192 x 32)
  int*   i1  = (int*)  (ws + (41u << 20));
  float* v2  = (float*)(ws + (42u << 20));
  int*   i2  = (int*)  (ws + (43u << 20));
  float* wsc = (float*)(ws + (44u << 20));       // softmax weights
  int*   fid = (int*)  (ws + (45u << 20));       // flat value indices

  // q = x @ Wq^T + bq   (2048x1024, K=1024)
  gemm_nt_f32<<<dim3(1024/64, 2048/128), 256, 0, stream>>>(x, 1024, Wq, 1024, q, 1024, bq, 1024);
  // s1 = q1 @ keys^T, s2 = q2 @ keys^T  (8192x512, K=128)
  gemm_nt_f32<<<dim3(512/64, 8192/128), 256, 0, stream>>>(q,       256, keys, 128, s1, 512, nullptr, 128);
  gemm_nt_f32<<<dim3(512/64, 8192/128), 256, 0, stream>>>(q + 128, 256, keys, 128, s2, 512, nullptr, 128);
  // per-row top-32 of 512 (both halves), sorted descending
  topk512<<<4096, 256, 0, stream>>>(s1, s2, v1, i1, v2, i2);
  // pairwise top-32 + softmax
  combine_topk<<<2048, 256, 0, stream>>>(v1, i1, v2, i2, wsc, fid);
  // weighted gather
  gather_wsum<<<2048, 256, 0, stream>>>(wsc, fid, values, out);
}